// Round 4
// baseline (114.366 us; speedup 1.0000x reference)
//
#include <hip/hip_runtime.h>

// out[b,h,t,r] = sum_d q[b,h,t,d] * emb[h, idx[r,t], d],  idx[r,t]=(t-r) mod 1023.
// Write-bound (out=67MB). Banded bf16 MFMA GEMM with DIRECT de-diagonalized
// stores: lane holds P[u][nb]; out element is (u, v=u-nb+63), stored iff
// 0<=v<64. Per store-inst each quad writes 16 consecutive dwords in one row
// -> coalesced. No LDS, no barriers; waves fully independent.

#define TOKENS 512
#define DIMH 64
#define NREL 1023
#define IDXN 1490

typedef short bf16x8 __attribute__((ext_vector_type(8)));
typedef float f32x4 __attribute__((ext_vector_type(4)));

__device__ __forceinline__ short f2bf(float x) {  // RNE fp32->bf16
    unsigned u = __float_as_uint(x);
    return (short)((u + 0x7FFFu + ((u >> 16) & 1u)) >> 16);
}
__device__ __forceinline__ bf16x8 cvt8(float4 a, float4 b) {
    bf16x8 r;
    r[0] = f2bf(a.x); r[1] = f2bf(a.y); r[2] = f2bf(a.z); r[3] = f2bf(a.w);
    r[4] = f2bf(b.x); r[5] = f2bf(b.y); r[6] = f2bf(b.z); r[7] = f2bf(b.w);
    return r;
}

__global__ __launch_bounds__(256, 4)
void relpos_direct(const float* __restrict__ q,
                   const float* __restrict__ emb,
                   const int* __restrict__ indices,
                   float* __restrict__ out)
{
    const int tid = threadIdx.x;
    const int blk = blockIdx.x;       // 1024 = rh(2) x tt(8) x bh(64)
    const int rh = blk & 1;
    const int tt = (blk >> 1) & 7;
    const int bh = blk >> 4;
    const int h  = bh & 7;
    const int t0 = tt * 64;

    const int lane = tid & 63;
    const int wave = tid >> 6;
    const int quad = lane >> 4;
    const int l15  = lane & 15;

    // ---- A fragments: once per block, global -> regs (A[m=l15][k=quad*8+j])
    bf16x8 af[4][2];
    {
        const float* qb = q + ((size_t)bh * TOKENS + t0 + l15) * DIMH + quad * 8;
#pragma unroll
        for (int mi = 0; mi < 4; ++mi) {
            const float* p0 = qb + (size_t)mi * 16 * DIMH;
            float4 a0 = *(const float4*)p0;
            float4 a1 = *(const float4*)(p0 + 4);
            float4 b0 = *(const float4*)(p0 + 32);
            float4 b1 = *(const float4*)(p0 + 36);
            af[mi][0] = cvt8(a0, a1);
            af[mi][1] = cvt8(b0, b1);
        }
    }

    // ---- band anchors for all 4 r-subtiles (honest indices reads)
    int ja[4];
#pragma unroll
    for (int rt = 0; rt < 4; ++rt)
        ja[rt] = indices[(size_t)(rh * 256 + rt * 64 + 63) * IDXN + t0];

    const float* embh = emb + (size_t)h * NREL * DIMH;
    const int nb0 = wave * 32 + l15;             // nn=0 band col for this lane

    // elem addr = out + (bh*512+t0)*512 + rh*256 + 63 + u*513 - nb + rt*64
    float* outq = out + ((size_t)bh * TOKENS + t0) * (size_t)TOKENS
                + rh * 256 + 63 + quad * 4 * 513 - nb0;

    for (int rt = 0; rt < 4; ++rt) {
        // ---- B fragments: row j = (ja + nb) mod 1023, k-chunk = quad*8
        bf16x8 bfr[2][2];
#pragma unroll
        for (int nn = 0; nn < 2; ++nn) {
            int j = ja[rt] + nb0 + nn * 16;
            if (j >= NREL) j -= NREL;
            const float* ep = embh + (size_t)j * DIMH + quad * 8;
            float4 a0 = *(const float4*)ep;
            float4 a1 = *(const float4*)(ep + 4);
            float4 b0 = *(const float4*)(ep + 32);
            float4 b1 = *(const float4*)(ep + 36);
            bfr[nn][0] = cvt8(a0, a1);
            bfr[nn][1] = cvt8(b0, b1);
        }

        float* outr = outq + rt * 64;
#pragma unroll
        for (int nn = 0; nn < 2; ++nn) {
            const int nbq = quad * 4 - (nb0 + nn * 16) + 63;  // v - (mi*16+rg)
#pragma unroll
            for (int mi = 0; mi < 4; ++mi) {
                f32x4 acc = {0.f, 0.f, 0.f, 0.f};
                acc = __builtin_amdgcn_mfma_f32_16x16x32_bf16(af[mi][0], bfr[nn][0], acc, 0, 0, 0);
                acc = __builtin_amdgcn_mfma_f32_16x16x32_bf16(af[mi][1], bfr[nn][1], acc, 0, 0, 0);
#pragma unroll
                for (int rg = 0; rg < 4; ++rg) {
                    const int v = nbq + mi * 16 + rg;         // u - nb + 63
                    if ((unsigned)v < 64u)
                        outr[(size_t)(mi * 16 + rg) * 513 - nn * 16] = acc[rg];
                }
            }
        }
    }
}

extern "C" void kernel_launch(void* const* d_in, const int* in_sizes, int n_in,
                              void* d_out, int out_size, void* d_ws, size_t ws_size,
                              hipStream_t stream) {
    const float* q       = (const float*)d_in[0];
    const float* emb     = (const float*)d_in[1];
    const int*   indices = (const int*)d_in[2];
    float* out = (float*)d_out;

    relpos_direct<<<dim3(1024), dim3(256), 0, stream>>>(q, emb, indices, out);
}

// Round 5
// 96.761 us; speedup vs baseline: 1.1820x; 1.1820x over previous
//
#include <hip/hip_runtime.h>

// out[b,h,t,r] = sum_d q[b,h,t,d] * emb[h, idx[r,t], d],  idx[r,t]=(t-r) mod 1023.
// 64x64 (t,r) tiles. E band (128 rows) staged coalesced into LDS (bf16) once per
// block. Each wave owns 16 t-rows: computes the 5 16-col band blocks those rows
// need (10 MFMAs), writes P to a WAVE-PRIVATE LDS slice, then de-diagonalizes
// into aligned float4 stores. One barrier per block; no inter-wave coupling.

#define TOKENS 512
#define DIMH 64
#define NREL 1023
#define IDXN 1490

#define ESTR 72      // shorts per Es row (64 + 8 pad) = 144 B (16B-aligned rows)
#define PSTR 17      // dwords per Ps column (16 rows + 1 pad)
#define PCOLS 80     // band cols per wave (5 blocks of 16)

typedef short bf16x8 __attribute__((ext_vector_type(8)));
typedef float f32x4 __attribute__((ext_vector_type(4)));

__device__ __forceinline__ unsigned short f2bf(float x) {  // RNE fp32->bf16
    unsigned u = __float_as_uint(x);
    return (unsigned short)((u + 0x7FFFu + ((u >> 16) & 1u)) >> 16);
}
__device__ __forceinline__ bf16x8 cvt8(float4 a, float4 b) {
    bf16x8 r;
    r[0] = (short)f2bf(a.x); r[1] = (short)f2bf(a.y);
    r[2] = (short)f2bf(a.z); r[3] = (short)f2bf(a.w);
    r[4] = (short)f2bf(b.x); r[5] = (short)f2bf(b.y);
    r[6] = (short)f2bf(b.z); r[7] = (short)f2bf(b.w);
    return r;
}

__global__ __launch_bounds__(256, 4)
void relpos_wave(const float* __restrict__ q,
                 const float* __restrict__ emb,
                 const int* __restrict__ indices,
                 float* __restrict__ out)
{
    __shared__ unsigned short Es[128 * ESTR];   // 18432 B, read-only after barrier
    __shared__ float Ps[4 * PCOLS * PSTR];      // 21760 B, wave-private slices

    const int tid = threadIdx.x;
    const int blk = blockIdx.x;        // 4096 = rt(8) x tt(8) x bh(64)
    const int rt = blk & 7;
    const int tt = (blk >> 3) & 7;
    const int bh = blk >> 6;
    const int h  = bh & 7;
    const int t0 = tt * 64;
    const int r0 = rt * 64;

    // honest indices read: j_a = idx[r0+63, t0] = (t0 - r0 - 63) mod 1023
    const int j_a = indices[(size_t)(r0 + 63) * IDXN + t0];

    const int lane = tid & 63;
    const int wave = tid >> 6;
    const int quad = lane >> 4;
    const int l15  = lane & 15;

    // ---- stage E band: rows j_a+0 .. j_a+127 (mod 1023), fp32 -> bf16, coalesced
    {
        const float* embh = emb + (size_t)h * NREL * DIMH;
        const int c16 = tid & 15;            // float4 column within row
        const int rbase = tid >> 4;          // 16 rows per pass
#pragma unroll
        for (int it = 0; it < 8; ++it) {
            const int row = rbase + it * 16;
            int j = j_a + row;
            if (j >= NREL) j -= NREL;
            const float4 v = *(const float4*)(embh + (size_t)j * DIMH + c16 * 4);
            ushort4 w = { f2bf(v.x), f2bf(v.y), f2bf(v.z), f2bf(v.w) };
            *(ushort4*)(Es + (size_t)row * ESTR + c16 * 4) = w;
        }
    }

    // ---- A fragment: wave owns rows t = t0 + wave*16 + m,  A[m=l15][k=quad*8+j]
    bf16x8 af0, af1;
    {
        const float* qp = q + ((size_t)bh * TOKENS + t0 + wave * 16 + l15) * DIMH
                        + quad * 8;
        float4 a0 = *(const float4*)qp;
        float4 a1 = *(const float4*)(qp + 4);
        float4 c0 = *(const float4*)(qp + 32);
        float4 c1 = *(const float4*)(qp + 36);
        af0 = cvt8(a0, a1);
        af1 = cvt8(c0, c1);
    }

    __syncthreads();   // the only barrier: Es staged; Es is read-only hereafter

    float* psw = Ps + (size_t)wave * (PCOLS * PSTR);

    // ---- 5 n-blocks: band cols nb = wave*16 + i*16 + l15 (local col 16i+l15)
#pragma unroll
    for (int i = 0; i < 5; ++i) {
        const unsigned short* bp = Es + (size_t)(wave * 16 + i * 16 + l15) * ESTR
                                 + quad * 8;
        bf16x8 b0 = *(const bf16x8*)bp;          // 144B rows -> 16B aligned
        bf16x8 b1 = *(const bf16x8*)(bp + 32);
        f32x4 acc = {0.f, 0.f, 0.f, 0.f};
        acc = __builtin_amdgcn_mfma_f32_16x16x32_bf16(af0, b0, acc, 0, 0, 0);
        acc = __builtin_amdgcn_mfma_f32_16x16x32_bf16(af1, b1, acc, 0, 0, 0);
        // D[m=quad*4+rg][n=l15] -> Ps_T[col=16i+l15][row=m]
        float* pw = psw + (size_t)(i * 16 + l15) * PSTR + quad * 4;
        pw[0] = acc[0]; pw[1] = acc[1]; pw[2] = acc[2]; pw[3] = acc[3];
    }

    // ---- epilogue (same wave; ordered by lgkmcnt, no barrier):
    // out[t0+16w+u][r0+v] = Ps_T[u+63-v][u],  u in [0,16), v in [0,64)
    const int v16 = l15;                 // v4 = v16*4 ; 16 lanes -> 256B run
    const int ug  = quad;               // u = ug + 4p
    float* ob = out + ((size_t)(bh * TOKENS + t0 + wave * 16)) * TOKENS
              + r0 + v16 * 4;
#pragma unroll
    for (int p = 0; p < 4; ++p) {
        const int u = ug + p * 4;
        const int colbase = u + 63 - v16 * 4;     // in [3, 78]
        float4 o;
        o.x = psw[(size_t)(colbase    ) * PSTR + u];
        o.y = psw[(size_t)(colbase - 1) * PSTR + u];
        o.z = psw[(size_t)(colbase - 2) * PSTR + u];
        o.w = psw[(size_t)(colbase - 3) * PSTR + u];
        *(float4*)(ob + (size_t)u * TOKENS) = o;
    }
}

extern "C" void kernel_launch(void* const* d_in, const int* in_sizes, int n_in,
                              void* d_out, int out_size, void* d_ws, size_t ws_size,
                              hipStream_t stream) {
    const float* q       = (const float*)d_in[0];
    const float* emb     = (const float*)d_in[1];
    const int*   indices = (const int*)d_in[2];
    float* out = (float*)d_out;

    relpos_wave<<<dim3(4096), dim3(256), 0, stream>>>(q, emb, indices, out);
}